// Round 4
// baseline (211.793 us; speedup 1.0000x reference)
//
#include <hip/hip_runtime.h>
#include <hip/hip_bf16.h>

typedef unsigned short u16;
typedef unsigned int u32;
using short8  = __attribute__((ext_vector_type(8))) short;
using floatx4 = __attribute__((ext_vector_type(4))) float;
using uint2v  = __attribute__((ext_vector_type(2))) unsigned int;

#define KPAD 104   // LDS row stride (bf16): 52 dwords, %32=20 -> b128 frag reads 2-way (free)
#define VSTR 96    // global V row stride (bf16): 192 B, 16B-aligned rows

__device__ __forceinline__ u16 f2bf(float f) {
  union { float f; unsigned u; } v; v.f = f;
  unsigned r = v.u + 0x7fffu + ((v.u >> 16) & 1u);   // RNE
  return (u16)(r >> 16);
}

// ---------------- Kernel 1: conv1x1+bias+unfold (y=0,1) and W_eff (y=2) ----------------
// V layout: row = (tensor*32 + o)*1024 + l, stride VSTR; l = pd*256+pw, k = kd*9+kw.
// wepad: bf16 [96][104], W_eff[kp][k] = sum_m W2[kp][m]*W1[m][k], zero outside 81x81.
__global__ __launch_bounds__(256) void k_conv(const float* __restrict__ xg,
                                              const float* __restrict__ yg,
                                              const float* __restrict__ Wi,
                                              const float* __restrict__ bi,
                                              const float* __restrict__ Wf,
                                              const float* __restrict__ bfe,
                                              const float* __restrict__ W1,
                                              const float* __restrict__ W2,
                                              u16* __restrict__ V,
                                              u16* __restrict__ wepad) {
  int t = threadIdx.x;
  if (blockIdx.y == 2) {                 // ---- W_eff blocks ----
    if (blockIdx.x >= 39) return;        // 39*256 = 9984 = 96*104
    int idx = blockIdx.x * 256 + t;
    int kp = idx / 104, k = idx - kp * 104;
    float s = 0.f;
    if (kp < 81 && k < 81) {
      #pragma unroll 6
      for (int m = 0; m < 162; ++m)
        s = fmaf(W2[kp * 162 + m], W1[m * 81 + k], s);
    }
    wepad[idx] = (kp < 81 && k < 81) ? f2bf(s) : (u16)0;
    return;
  }
  // ---- conv blocks ----
  __shared__ float Ws[1024];
  __shared__ float bs[32];
  int tensor = blockIdx.y;
  const float* src = tensor ? yg : xg;
  const float* Wg  = tensor ? Wf : Wi;
  const float* bg  = tensor ? bfe : bi;
  for (int i = t; i < 1024; i += 256) Ws[i] = Wg[i];
  if (t < 32) bs[t] = bg[t];
  __syncthreads();

  int vbase = blockIdx.x * 512 + t;       // 162 blocks * 512 = 82944 voxels
  float xin[2][32];
  #pragma unroll
  for (int c = 0; c < 32; ++c) {
    xin[0][c] = src[c * 82944 + vbase];
    xin[1][c] = src[c * 82944 + vbase + 256];
  }
  int dst[2];
  #pragma unroll
  for (int v = 0; v < 2; ++v) {
    int vox = vbase + v * 256;
    int d  = vox / 2304, hw = vox - d * 2304;
    int pd = d / 9,  kd = d  - pd * 9;
    int pw = hw / 9, kw = hw - pw * 9;
    dst[v] = tensor * (32 * 1024 * VSTR) + (pd * 256 + pw) * VSTR + kd * 9 + kw;
  }
  #pragma unroll
  for (int o = 0; o < 32; ++o) {
    float s0 = bs[o], s1 = bs[o];
    #pragma unroll
    for (int c = 0; c < 32; ++c) {
      float w = Ws[o * 32 + c];
      s0 = fmaf(w, xin[0][c], s0);
      s1 = fmaf(w, xin[1][c], s1);
    }
    V[dst[0] + o * (1024 * VSTR)] = f2bf(s0);
    V[dst[1] + o * (1024 * VSTR)] = f2bf(s1);
  }
}

// ---------------- Kernel 2: fused res_trans + att ----------------
// grid (8,8,32): out tile 128(l1) x 128(l2) for channel c.
// Phase B uses A=WeT, B=V so each lane holds 4 consecutive kp -> ds_write_b64.
// Phase C uses A=PY(l2), B=PX(l1) so each lane holds 4 consecutive l2 -> dwordx4 stores.
__global__ __launch_bounds__(256, 2) void k_att(const u16* __restrict__ V,
                                                const u16* __restrict__ wepad,
                                                float* __restrict__ out) {
  __shared__ u16 WeT[96 * KPAD];    // 19968 B
  __shared__ u16 pxs[128 * KPAD];   // 26624 B
  __shared__ u16 pys[128 * KPAD];   // 26624 B  (73216 B total -> 2 blocks/CU)
  int t = threadIdx.x;
  int c = blockIdx.z;
  int l1b = blockIdx.y * 128, l2b = blockIdx.x * 128;
  const u16* vx = V + ((c)      * 1024 + l1b) * VSTR;
  const u16* vy = V + ((32 + c) * 1024 + l2b) * VSTR;

  // --- Phase A: vectorized staging ---
  for (int i = t; i < 1248; i += 256)      // 96*104 = 1248 short8, direct copy
    *(short8*)&WeT[i * 8] = ((const short8*)wepad)[i];
  for (int i = t; i < 1536; i += 256) {    // 128 rows x 12 short8
    int r = i / 12, xx = i - r * 12;
    short8 a = *(const short8*)&vx[i * 8];  // i*8 == r*96 + xx*8
    short8 b = *(const short8*)&vy[i * 8];
    *(short8*)&pxs[r * KPAD + xx * 8] = a;
    *(short8*)&pys[r * KPAD + xx * 8] = b;
  }
  __syncthreads();

  int wave = t >> 6, lane = t & 63;
  int m15 = lane & 15, quad = lane >> 4;
  int wbase = wave * 32;

  // --- Phase B: P = LeakyReLU(V @ WeT^T) for this wave's 32 rows, in place ---
  // Preload ALL V fragments first (writes below overwrite these LDS rows).
  short8 av[2][2][3];   // [tz][ltile][ks]
  #pragma unroll
  for (int tz = 0; tz < 2; ++tz) {
    const u16* buf = tz ? pys : pxs;
    #pragma unroll
    for (int lt = 0; lt < 2; ++lt)
      #pragma unroll
      for (int ks = 0; ks < 3; ++ks)
        av[tz][lt][ks] = *(const short8*)&buf[(wbase + lt * 16 + m15) * KPAD + ks * 32 + quad * 8];
  }
  #pragma unroll
  for (int kptile = 0; kptile < 6; ++kptile) {
    short8 aw[3];
    #pragma unroll
    for (int ks = 0; ks < 3; ++ks)
      aw[ks] = *(const short8*)&WeT[(kptile * 16 + m15) * KPAD + ks * 32 + quad * 8];
    floatx4 pacc[2][2];
    #pragma unroll
    for (int tz = 0; tz < 2; ++tz)
      #pragma unroll
      for (int lt = 0; lt < 2; ++lt) pacc[tz][lt] = (floatx4){0.f, 0.f, 0.f, 0.f};
    #pragma unroll
    for (int ks = 0; ks < 3; ++ks)
      #pragma unroll
      for (int tz = 0; tz < 2; ++tz)
        #pragma unroll
        for (int lt = 0; lt < 2; ++lt)
          pacc[tz][lt] = __builtin_amdgcn_mfma_f32_16x16x32_bf16(aw[ks], av[tz][lt][ks], pacc[tz][lt], 0, 0, 0);
    // lane holds kp = kptile*16 + quad*4 + r (r=0..3), l = wbase + lt*16 + m15
    #pragma unroll
    for (int tz = 0; tz < 2; ++tz) {
      u16* buf = tz ? pys : pxs;
      #pragma unroll
      for (int lt = 0; lt < 2; ++lt) {
        u16 h[4];
        #pragma unroll
        for (int r = 0; r < 4; ++r) {
          float v = pacc[tz][lt][r];
          v = v > 0.f ? v : 0.2f * v;
          h[r] = f2bf(v);
        }
        u32 w0 = (u32)h[0] | ((u32)h[1] << 16);
        u32 w1 = (u32)h[2] | ((u32)h[3] << 16);
        int l = wbase + lt * 16 + m15;
        *(uint2v*)&buf[l * KPAD + kptile * 16 + quad * 4] = (uint2v){w0, w1};
      }
    }
  }
  __syncthreads();

  // --- Phase C: att tile; A=pys rows (l2), B=pxs rows (l1) ---
  int wy = (wave >> 1) * 64;   // l1 base for this wave
  int wx = (wave & 1) * 64;    // l2 base for this wave
  floatx4 acc[4][4];           // [a over l2][b over l1]
  #pragma unroll
  for (int a = 0; a < 4; ++a)
    #pragma unroll
    for (int b = 0; b < 4; ++b) acc[a][b] = (floatx4){0.f, 0.f, 0.f, 0.f};

  #pragma unroll
  for (int ks = 0; ks < 3; ++ks) {
    short8 a4[4], b4[4];
    #pragma unroll
    for (int a = 0; a < 4; ++a)
      a4[a] = *(const short8*)&pys[(wx + a * 16 + m15) * KPAD + ks * 32 + quad * 8];
    #pragma unroll
    for (int b = 0; b < 4; ++b)
      b4[b] = *(const short8*)&pxs[(wy + b * 16 + m15) * KPAD + ks * 32 + quad * 8];
    #pragma unroll
    for (int a = 0; a < 4; ++a)
      #pragma unroll
      for (int b = 0; b < 4; ++b)
        acc[a][b] = __builtin_amdgcn_mfma_f32_16x16x32_bf16(a4[a], b4[b], acc[a][b], 0, 0, 0);
  }

  const float inv = 1.f / 81.f;
  #pragma unroll
  for (int a = 0; a < 4; ++a)
    #pragma unroll
    for (int b = 0; b < 4; ++b) {
      int l1 = l1b + wy + b * 16 + m15;                 // row
      int l2 = l2b + wx + a * 16 + quad * 4;            // col base (4 consecutive)
      floatx4 vv;
      #pragma unroll
      for (int r = 0; r < 4; ++r) vv[r] = acc[a][b][r] * inv;
      *(floatx4*)&out[(c << 20) + (l1 << 10) + l2] = vv;
    }
}

extern "C" void kernel_launch(void* const* d_in, const int* in_sizes, int n_in,
                              void* d_out, int out_size, void* d_ws, size_t ws_size,
                              hipStream_t stream) {
  const float* x    = (const float*)d_in[0];
  const float* y    = (const float*)d_in[1];
  const float* Wimg = (const float*)d_in[2];
  const float* bimg = (const float*)d_in[3];
  const float* Wfea = (const float*)d_in[4];
  const float* bfea = (const float*)d_in[5];
  const float* W1   = (const float*)d_in[6];
  const float* W2   = (const float*)d_in[7];
  float* out = (float*)d_out;

  char* ws = (char*)d_ws;
  u16* wepad = (u16*)ws;                       //     19,968 B (96*104 bf16)
  u16* V     = (u16*)(ws + 32768);             // 12,582,912 B (65536 rows * 96 bf16)

  // zero V so pad cols 81..95 of every row are 0 (staging vector-loads them)
  hipMemsetAsync(V, 0, 65536 * (size_t)VSTR * 2, stream);
  k_conv<<<dim3(162, 3), 256, 0, stream>>>(x, y, Wimg, bimg, Wfea, bfea, W1, W2, V, wepad);
  k_att<<<dim3(8, 8, 32), 256, 0, stream>>>(V, wepad, out);
}